// Round 3
// baseline (434.560 us; speedup 1.0000x reference)
//
#include <hip/hip_runtime.h>
#include <cmath>

#define T_DIM 1024

// ---------------------------------------------------------------------------
// Kernel 1: fp64-accurate GEMM for a T-chunk (fp32 in, fp64 out).
//   Rows R in [0, 64*tc): R = b*tc + tl, input row = b*1024 + t0 + tl.
//   xbuf[R*256 + c] = sum_k (double)in[row][k] * (double)w[k][c]
// grid.x = (64*tc)/32 blocks (32 rows x all 256 cols), 256 threads.
// Thread: rows r4*4..+3  x  cols c0..c0+7, fp64 accumulators.
// A tile staged in LDS (full K=256); W read from global (L1/L2-resident 256 KiB).
// ---------------------------------------------------------------------------
__global__ __launch_bounds__(256) void lif_gemm(const float* __restrict__ in,
                                                const float* __restrict__ w,
                                                double* __restrict__ xbuf,
                                                int t0, int tc, int tcs) {
    __shared__ float As[32][260];     // 32 rows x 256 K, +4 pad

    const int tid = threadIdx.x;
    const int bm  = blockIdx.x;
    const int r4  = tid >> 5;         // 0..7 -> rows r4*4 .. r4*4+3
    const int c0  = (tid & 31) * 8;   // cols c0 .. c0+7

    // ---- stage A tile: row = tid>>3, 8 float4 segments per thread ----
    {
        const int r   = tid >> 3;              // 0..31
        const int seg = tid & 7;               // 0..7
        const int R   = bm * 32 + r;
        const int b   = R >> tcs;
        const int tl  = R & (tc - 1);
        const float* src = in + (size_t)(b * 1024 + t0 + tl) * 256;
        #pragma unroll
        for (int j = 0; j < 8; ++j) {
            const int f4 = seg + j * 8;        // float4 index 0..63
            *(float4*)&As[r][f4 * 4] = *(const float4*)(src + f4 * 4);
        }
    }
    __syncthreads();

    double acc[4][8];
    #pragma unroll
    for (int i = 0; i < 4; ++i)
        #pragma unroll
        for (int j = 0; j < 8; ++j) acc[i][j] = 0.0;

    const float* wp = w + c0;
    #pragma unroll 4
    for (int k = 0; k < 256; ++k) {
        float4 w0 = *(const float4*)(wp + (size_t)k * 256);
        float4 w1 = *(const float4*)(wp + (size_t)k * 256 + 4);
        double wd[8] = {(double)w0.x, (double)w0.y, (double)w0.z, (double)w0.w,
                        (double)w1.x, (double)w1.y, (double)w1.z, (double)w1.w};
        #pragma unroll
        for (int i = 0; i < 4; ++i) {
            const double a = (double)As[r4 * 4 + i][k];   // broadcast in half-wave
            #pragma unroll
            for (int j = 0; j < 8; ++j) acc[i][j] = fma(a, wd[j], acc[i][j]);
        }
    }

    const int Rb = bm * 32 + r4 * 4;
    #pragma unroll
    for (int i = 0; i < 4; ++i) {
        double* dst = xbuf + (size_t)(Rb + i) * 256 + c0;
        #pragma unroll
        for (int j = 0; j < 8; ++j) dst[j] = acc[i][j];
    }
}

// ---------------------------------------------------------------------------
// Kernel 2: LIF scan over a T-chunk. One thread per (b,o), fp64 state.
// grid = 256 blocks x 64 threads: b = blk>>2, o = (blk&3)*64 + tid.
// 16-deep load batches keep >=16 loads in flight per thread.
// ---------------------------------------------------------------------------
__global__ __launch_bounds__(64) void lif_scan(const double* __restrict__ xbuf,
                                               double* __restrict__ state,
                                               float* __restrict__ U,
                                               int t0, int tc, int nsteps,
                                               double dcy_syn, double dcy_mem,
                                               double scl_mem) {
    const int b = blockIdx.x >> 2;
    const int o = (blockIdx.x & 3) * 64 + threadIdx.x;
    const int nid = b * 256 + o;

    double syn, mem;
    if (t0 == 0) {
        syn = 0.0;
        mem = 0.0;
        U[(size_t)b * T_DIM * 256 + o] = 0.0f;     // stored initial state
    } else {
        syn = state[nid];
        mem = state[16384 + nid];
    }

    const double* xp = xbuf + (size_t)b * tc * 256 + o;
    float* up = U + (size_t)b * T_DIM * 256 + o;

    int tl = 0;
    for (; tl + 16 <= nsteps; tl += 16) {
        double xr[16];
        #pragma unroll
        for (int j = 0; j < 16; ++j) xr[j] = xp[(size_t)(tl + j) * 256];
        #pragma unroll
        for (int j = 0; j < 16; ++j) {
            double nm = dcy_mem * mem + scl_mem * syn;
            if (mem - 1.0 > 0.0) nm = 0.0;
            syn = dcy_syn * syn + xr[j];
            mem = nm;
            up[(size_t)(t0 + tl + j + 1) * 256] = (float)mem;
        }
    }
    for (; tl < nsteps; ++tl) {
        const double x = xp[(size_t)tl * 256];
        double nm = dcy_mem * mem + scl_mem * syn;
        if (mem - 1.0 > 0.0) nm = 0.0;
        syn = dcy_syn * syn + x;
        mem = nm;
        up[(size_t)(t0 + tl + 1) * 256] = (float)mem;
    }

    state[nid] = syn;
    state[16384 + nid] = mem;
}

// ---------------------------------------------------------------------------
// Zero-workspace fallback: fused GEMM+scan, correct but slow.
// grid = 256 blocks (b*4 + o-group), 64 threads (one o each).
// ---------------------------------------------------------------------------
__global__ __launch_bounds__(64) void lif_fused(const float* __restrict__ in,
                                                const float* __restrict__ w,
                                                float* __restrict__ U,
                                                double dcy_syn, double dcy_mem,
                                                double scl_mem) {
    __shared__ float wl[256 * 64];    // w[k][og*64+o] slice (64 KiB)
    __shared__ float xrow[256];

    const int b  = blockIdx.x >> 2;
    const int og = blockIdx.x & 3;
    const int o  = threadIdx.x;       // 0..63
    const int oc = og * 64 + o;

    for (int k = 0; k < 256; ++k) wl[k * 64 + o] = w[k * 256 + oc];

    double syn = 0.0, mem = 0.0;
    U[(size_t)b * T_DIM * 256 + oc] = 0.0f;

    for (int t = 0; t < T_DIM - 1; ++t) {
        __syncthreads();              // protect previous xrow reads
        #pragma unroll
        for (int k4 = 0; k4 < 4; ++k4)
            xrow[k4 * 64 + o] = in[(size_t)(b * 1024 + t) * 256 + k4 * 64 + o];
        __syncthreads();

        double x = 0.0;
        #pragma unroll 8
        for (int k = 0; k < 256; ++k)
            x = fma((double)xrow[k], (double)wl[k * 64 + o], x);

        double nm = dcy_mem * mem + scl_mem * syn;
        if (mem - 1.0 > 0.0) nm = 0.0;
        syn = dcy_syn * syn + x;
        mem = nm;
        U[(size_t)(b * 1024 + t + 1) * 256 + oc] = (float)mem;
    }
}

extern "C" void kernel_launch(void* const* d_in, const int* in_sizes, int n_in,
                              void* d_out, int out_size, void* d_ws, size_t ws_size,
                              hipStream_t stream) {
    const float* in = (const float*)d_in[0];   // fp32 [64][1024][256]
    const float* w  = (const float*)d_in[1];   // fp32 [256][256]
    float* U = (float*)d_out;                  // fp32 [64][1024][256]

    // fp64 constants, as a numpy re-evaluation of the reference computes them
    const double dcy_mem = exp(-0.001 / (0.01  + 1e-16));
    const double dcy_syn = exp(-0.001 / (0.005 + 1e-16));
    const double scl_mem = 1.0 - dcy_mem;

    // workspace layout: state (256 KiB) | xbuf (Tc * 128 KiB fp64)
    double* state = (double*)d_ws;
    double* xbuf  = (double*)((char*)d_ws + 262144);

    int Tc = 1024;
    while (Tc > 1 && 262144ull + (size_t)Tc * 131072ull > ws_size) Tc >>= 1;

    if (262144ull + (size_t)Tc * 131072ull <= ws_size) {
        const int tcs = __builtin_ctz((unsigned)Tc);
        for (int t0 = 0; t0 < T_DIM; t0 += Tc) {
            lif_gemm<<<dim3(2 * Tc), dim3(256), 0, stream>>>(in, w, xbuf, t0, Tc, tcs);
            int nsteps = (T_DIM - 1) - t0;
            if (nsteps > Tc) nsteps = Tc;
            if (nsteps > 0)
                lif_scan<<<dim3(256), dim3(64), 0, stream>>>(xbuf, state, U, t0, Tc, nsteps,
                                                             dcy_syn, dcy_mem, scl_mem);
        }
    } else {
        lif_fused<<<dim3(256), dim3(64), 0, stream>>>(in, w, U, dcy_syn, dcy_mem, scl_mem);
    }
}

// Round 4
// 206.437 us; speedup vs baseline: 2.1051x; 2.1051x over previous
//
#include <hip/hip_runtime.h>
#include <cmath>

typedef short bf16x8 __attribute__((ext_vector_type(8)));
typedef float f32x4 __attribute__((ext_vector_type(4)));
typedef unsigned short us4 __attribute__((ext_vector_type(4)));

#define T_DIM 1024
#define LDA 72        // A-limb LDS row stride in ushorts (64 + 8 pad; 144B = 16B-aligned rows)

__device__ __forceinline__ unsigned short rtn_bf16(float f) {
    unsigned u = __float_as_uint(f);
    return (unsigned short)((u + 0x7FFFu + ((u >> 16) & 1u)) >> 16);
}
__device__ __forceinline__ float bf_to_f(unsigned short h) {
    return __uint_as_float(((unsigned)h) << 16);
}

// ---------------------------------------------------------------------------
// Kernel 0: split w (fp32 [k][n]) into 3 bf16 limbs, TRANSPOSED: wT[n][k].
// a = a1 + a2 + a3 exactly (fp32 has 24 mantissa bits = 3 bf16 limbs).
// ---------------------------------------------------------------------------
__global__ __launch_bounds__(256) void lif_wsplit(const float* __restrict__ w,
                                                  unsigned short* __restrict__ wT1,
                                                  unsigned short* __restrict__ wT2,
                                                  unsigned short* __restrict__ wT3) {
    const int id = blockIdx.x * 256 + threadIdx.x;   // 65536 elements
    const int k = id >> 8, n = id & 255;
    const float f = w[id];                            // w[k][n]
    const unsigned short h1 = rtn_bf16(f);
    const float r1 = f - bf_to_f(h1);                 // exact
    const unsigned short h2 = rtn_bf16(r1);
    const float r2 = r1 - bf_to_f(h2);                // exact
    const unsigned short h3 = rtn_bf16(r2);
    const int o = n * 256 + k;
    wT1[o] = h1; wT2[o] = h2; wT3[o] = h3;
}

// ---------------------------------------------------------------------------
// Kernel 1: bf16-MFMA GEMM with 3-limb split of A (exact) and of W (precomputed).
//   x[R][c] = sum_k in[R][k] * w[k][c],  R = b*1024 + t in [0, 65536)
// 6 MFMA products per position: a1w1, a1w2, a2w1, a2w2, a1w3, a3w1
// (dropped terms < 2e-6 abs; single fp32 acc — rounding ~1.5e-5, below ref's own fp32 noise).
// Block: 128m x 128n, BK=64, 4 waves each 64x64. grid (512, 2).
// ---------------------------------------------------------------------------
__global__ __launch_bounds__(256) void lif_gemm_mfma(const float* __restrict__ in,
                                                     const unsigned short* __restrict__ wT1,
                                                     const unsigned short* __restrict__ wT2,
                                                     const unsigned short* __restrict__ wT3,
                                                     float* __restrict__ xbuf) {
    __shared__ unsigned short As[3][128 * LDA];   // 3 limb tiles, 54 KiB total

    const int tid  = threadIdx.x;
    const int bm   = blockIdx.x;           // 0..511 (128-row tiles)
    const int bn   = blockIdx.y;           // 0..1   (128-col tiles)
    const int wave = tid >> 6;
    const int lane = tid & 63;
    const int l15  = lane & 15;
    const int quad = lane >> 4;
    const int wm   = (wave >> 1) * 64;     // wave's 64x64 sub-tile
    const int wn   = (wave & 1) * 64;

    f32x4 acc[4][4];
    #pragma unroll
    for (int i = 0; i < 4; ++i)
        #pragma unroll
        for (int j = 0; j < 4; ++j) acc[i][j] = (f32x4){0.f, 0.f, 0.f, 0.f};

    const int r  = tid >> 1;               // staging row 0..127
    const int hf = tid & 1;                // staging half
    const float* arow = in + (size_t)(bm * 128 + r) * 256;

    for (int kt = 0; kt < 4; ++kt) {
        const int k0 = kt * 64;
        // prefetch this chunk's A data to registers before the barrier
        float4 av[8];
        #pragma unroll
        for (int j = 0; j < 8; ++j)
            av[j] = *(const float4*)(arow + k0 + (hf * 8 + j) * 4);

        __syncthreads();                   // previous chunk fully consumed
        #pragma unroll
        for (int j = 0; j < 8; ++j) {
            const int kl = (hf * 8 + j) * 4;
            float fv[4] = {av[j].x, av[j].y, av[j].z, av[j].w};
            us4 o1, o2, o3;
            #pragma unroll
            for (int i = 0; i < 4; ++i) {
                const unsigned short h1 = rtn_bf16(fv[i]);
                const float r1 = fv[i] - bf_to_f(h1);
                const unsigned short h2 = rtn_bf16(r1);
                const float r2 = r1 - bf_to_f(h2);
                const unsigned short h3 = rtn_bf16(r2);
                o1[i] = h1; o2[i] = h2; o3[i] = h3;
            }
            *(us4*)&As[0][r * LDA + kl] = o1;
            *(us4*)&As[1][r * LDA + kl] = o2;
            *(us4*)&As[2][r * LDA + kl] = o3;
        }
        __syncthreads();

        #pragma unroll
        for (int ks = 0; ks < 2; ++ks) {
            // A fragments: A[m = l15][k = quad*8 + j] (verified layout)
            bf16x8 af[3][4];
            #pragma unroll
            for (int mt = 0; mt < 4; ++mt) {
                const int row = wm + mt * 16 + l15;
                const int ko  = ks * 32 + quad * 8;
                af[0][mt] = *(const bf16x8*)&As[0][row * LDA + ko];
                af[1][mt] = *(const bf16x8*)&As[1][row * LDA + ko];
                af[2][mt] = *(const bf16x8*)&As[2][row * LDA + ko];
            }
            #pragma unroll
            for (int nt = 0; nt < 4; ++nt) {
                // B fragments from global wT (L2-resident): B[k=quad*8+j][n=l15]
                const int ncol = bn * 128 + wn + nt * 16 + l15;
                const size_t wo = (size_t)ncol * 256 + k0 + ks * 32 + quad * 8;
                const bf16x8 b1 = *(const bf16x8*)(wT1 + wo);
                const bf16x8 b2 = *(const bf16x8*)(wT2 + wo);
                const bf16x8 b3 = *(const bf16x8*)(wT3 + wo);
                #pragma unroll
                for (int mt = 0; mt < 4; ++mt) {
                    f32x4 a = acc[mt][nt];
                    a = __builtin_amdgcn_mfma_f32_16x16x32_bf16(af[0][mt], b1, a, 0, 0, 0);
                    a = __builtin_amdgcn_mfma_f32_16x16x32_bf16(af[0][mt], b2, a, 0, 0, 0);
                    a = __builtin_amdgcn_mfma_f32_16x16x32_bf16(af[1][mt], b1, a, 0, 0, 0);
                    a = __builtin_amdgcn_mfma_f32_16x16x32_bf16(af[1][mt], b2, a, 0, 0, 0);
                    a = __builtin_amdgcn_mfma_f32_16x16x32_bf16(af[0][mt], b3, a, 0, 0, 0);
                    a = __builtin_amdgcn_mfma_f32_16x16x32_bf16(af[2][mt], b1, a, 0, 0, 0);
                    acc[mt][nt] = a;
                }
            }
        }
    }

    // epilogue: C/D layout col=lane&15, row=(lane>>4)*4+reg (verified m89)
    #pragma unroll
    for (int mt = 0; mt < 4; ++mt) {
        #pragma unroll
        for (int nt = 0; nt < 4; ++nt) {
            const int C = bn * 128 + wn + nt * 16 + l15;
            const int Rb = bm * 128 + wm + mt * 16 + quad * 4;
            #pragma unroll
            for (int reg = 0; reg < 4; ++reg)
                xbuf[(size_t)(Rb + reg) * 256 + C] = acc[mt][nt][reg];
        }
    }
}

// ---------------------------------------------------------------------------
// Kernel 2: LIF scan, full T in one launch. One thread per (b,o), fp64 state.
// 256 blocks x 64 threads (one wave/CU — chain-parallelism-limited);
// 32-deep load batches keep 32 loads in flight per thread.
// ---------------------------------------------------------------------------
__global__ __launch_bounds__(64) void lif_scan(const float* __restrict__ xbuf,
                                               float* __restrict__ U,
                                               double dcy_syn, double dcy_mem,
                                               double scl_mem) {
    const int b = blockIdx.x >> 2;
    const int o = (blockIdx.x & 3) * 64 + threadIdx.x;

    double syn = 0.0, mem = 0.0;
    U[(size_t)b * T_DIM * 256 + o] = 0.0f;     // stored initial state

    const float* xp = xbuf + (size_t)b * T_DIM * 256 + o;
    float* up = U + (size_t)b * T_DIM * 256 + o;

    int tl = 0;
    for (; tl + 32 <= T_DIM - 1; tl += 32) {
        float xr[32];
        #pragma unroll
        for (int j = 0; j < 32; ++j) xr[j] = xp[(size_t)(tl + j) * 256];
        #pragma unroll
        for (int j = 0; j < 32; ++j) {
            double nm = dcy_mem * mem + scl_mem * syn;
            if (mem - 1.0 > 0.0) nm = 0.0;
            syn = dcy_syn * syn + (double)xr[j];
            mem = nm;
            up[(size_t)(tl + j + 1) * 256] = (float)mem;
        }
    }
    for (; tl < T_DIM - 1; ++tl) {
        const double x = (double)xp[(size_t)tl * 256];
        double nm = dcy_mem * mem + scl_mem * syn;
        if (mem - 1.0 > 0.0) nm = 0.0;
        syn = dcy_syn * syn + x;
        mem = nm;
        up[(size_t)(tl + 1) * 256] = (float)mem;
    }
}

extern "C" void kernel_launch(void* const* d_in, const int* in_sizes, int n_in,
                              void* d_out, int out_size, void* d_ws, size_t ws_size,
                              hipStream_t stream) {
    const float* in = (const float*)d_in[0];   // fp32 [64][1024][256]
    const float* w  = (const float*)d_in[1];   // fp32 [256][256]
    float* U = (float*)d_out;                  // fp32 [64][1024][256]

    const double dcy_mem = exp(-0.001 / (0.01  + 1e-16));
    const double dcy_syn = exp(-0.001 / (0.005 + 1e-16));
    const double scl_mem = 1.0 - dcy_mem;

    // ws layout: wT1|wT2|wT3 (3 x 128 KiB bf16) | xbuf (64 MiB fp32)
    // (R3 ran with Tc=1024 => ws_size >= 134.5 MB, so this fits.)
    char* ws = (char*)d_ws;
    unsigned short* wT1 = (unsigned short*)ws;
    unsigned short* wT2 = (unsigned short*)(ws + 131072);
    unsigned short* wT3 = (unsigned short*)(ws + 262144);
    float* xbuf = (float*)(ws + 524288);

    lif_wsplit<<<dim3(256), dim3(256), 0, stream>>>(w, wT1, wT2, wT3);
    lif_gemm_mfma<<<dim3(512, 2), dim3(256), 0, stream>>>(in, wT1, wT2, wT3, xbuf);
    lif_scan<<<dim3(256), dim3(64), 0, stream>>>(xbuf, U, dcy_syn, dcy_mem, scl_mem);
}